// Round 1
// baseline (849.816 us; speedup 1.0000x reference)
//
#include <hip/hip_runtime.h>

#define HH 1024
#define WW 1024
#define NIMG 16
#define TX 32
#define TY 8
#define EPSF 1.1920929e-07f

__device__ __forceinline__ int clampi(int v, int hi) {
    return v < 0 ? 0 : (v > hi ? hi : v);
}
__device__ __forceinline__ int refli(int v, int n) {
    // jnp.pad mode='reflect': -1 -> 1, n -> n-2
    return v < 0 ? -v : (v >= n ? 2 * n - 2 - v : v);
}

__global__ __launch_bounds__(TX * TY) void nms_loss_kernel(
    const float* __restrict__ tru, const float* __restrict__ prd,
    float* __restrict__ out)
{
    __shared__ float s_t[TY + 4][TX + 4];   // true, clamp halo 2
    __shared__ float s_gx[TY + 2][TX + 2];  // sobel-x, clamp halo 1
    __shared__ float s_gy[TY + 2][TX + 2];  // sobel-y, clamp halo 1
    __shared__ float s_e[TY + 2][TX + 2];   // exp(pred), reflect halo 1
    __shared__ float s_red[(TX * TY) / 64];

    const int tid = threadIdx.y * TX + threadIdx.x;
    const int bx0 = blockIdx.x * TX;
    const int by0 = blockIdx.y * TY;
    const long imgoff = (long)blockIdx.z * (long)(HH * WW);
    const float* timg = tru + imgoff;
    const float* pimg = prd + imgoff;

    // stage 1a: true tile (clamp / replicate halo 2)
    for (int idx = tid; idx < (TY + 4) * (TX + 4); idx += TX * TY) {
        int r = idx / (TX + 4), c = idx % (TX + 4);
        int gy = clampi(by0 + r - 2, HH - 1);
        int gx = clampi(bx0 + c - 2, WW - 1);
        s_t[r][c] = timg[gy * WW + gx];
    }
    // stage 1b: exp(pred) tile (reflect halo 1)
    for (int idx = tid; idx < (TY + 2) * (TX + 2); idx += TX * TY) {
        int r = idx / (TX + 2), c = idx % (TX + 2);
        int gy = refli(by0 + r - 1, HH);
        int gx = refli(bx0 + c - 1, WW);
        s_e[r][c] = __expf(pimg[gy * WW + gx]);
    }
    __syncthreads();

    // stage 2: first sobel (gx, gy) at tile+halo1 positions.
    // Slot r holds value at global row clamp(by0+r-1); taps use nested clamp
    // then map the FULLY-CLAMPED global coordinate back to an s_t slot
    // (slot = g - by0 + 2), which preserves the per-stage replicate-pad
    // semantics at image borders.
    for (int idx = tid; idx < (TY + 2) * (TX + 2); idx += TX * TY) {
        int r = idx / (TX + 2), c = idx % (TX + 2);
        int g1y = clampi(by0 + r - 1, HH - 1);
        int g1x = clampi(bx0 + c - 1, WW - 1);
        int ym = clampi(g1y - 1, HH - 1) - by0 + 2;
        int y0 = g1y - by0 + 2;
        int yp = clampi(g1y + 1, HH - 1) - by0 + 2;
        int xm = clampi(g1x - 1, WW - 1) - bx0 + 2;
        int x0 = g1x - bx0 + 2;
        int xp = clampi(g1x + 1, WW - 1) - bx0 + 2;
        float tmm = s_t[ym][xm], tm0 = s_t[ym][x0], tmp_ = s_t[ym][xp];
        float t0m = s_t[y0][xm],                    t0p = s_t[y0][xp];
        float tpm = s_t[yp][xm], tp0 = s_t[yp][x0], tpp = s_t[yp][xp];
        // normalized sobel (sum |k| = 8)
        s_gx[r][c] = ((tmp_ - tmm) + 2.f * (t0p - t0m) + (tpp - tpm)) * 0.125f;
        s_gy[r][c] = ((tpm - tmm) + 2.f * (tp0 - tm0) + (tpp - tmp_)) * 0.125f;
    }
    __syncthreads();

    // stage 3: per-pixel second gradients, bin, NMS term
    const int y = by0 + threadIdx.y;
    const int x = bx0 + threadIdx.x;
    int rm = clampi(y - 1, HH - 1) - by0 + 1;
    int r0 = y - by0 + 1;
    int rp = clampi(y + 1, HH - 1) - by0 + 1;
    int cm = clampi(x - 1, WW - 1) - bx0 + 1;
    int c0 = x - bx0 + 1;
    int cp = clampi(x + 1, WW - 1) - bx0 + 1;

    float gxx = ((s_gx[rm][cp] - s_gx[rm][cm]) + 2.f * (s_gx[r0][cp] - s_gx[r0][cm])
               + (s_gx[rp][cp] - s_gx[rp][cm])) * 0.125f;
    float gxy = ((s_gy[rm][cp] - s_gy[rm][cm]) + 2.f * (s_gy[r0][cp] - s_gy[r0][cm])
               + (s_gy[rp][cp] - s_gy[rp][cm])) * 0.125f;
    float gyy = ((s_gy[rp][cm] - s_gy[rm][cm]) + 2.f * (s_gy[rp][c0] - s_gy[rm][c0])
               + (s_gy[rp][cp] - s_gy[rm][cp])) * 0.125f;

    float sarg = EPSF - gxy;
    float sgn = (sarg > 0.f) ? 1.f : ((sarg < 0.f) ? -1.f : 0.f);
    float v = gyy * sgn / (gxx + EPSF);

    // e-tile lookups (reflect)
    int erm = refli(y - 1, HH) - by0 + 1;
    int er0 = threadIdx.y + 1;
    int erp = refli(y + 1, HH) - by0 + 1;
    int ecm = refli(x - 1, WW) - bx0 + 1;
    int ec0 = threadIdx.x + 1;
    int ecp = refli(x + 1, WW) - bx0 + 1;
    float ec = s_e[er0][ec0];

    // bin = fmod(round(atan(v)*5/pi)+5,5) via tan thresholds:
    //   v >  tan(3pi/10)               -> k= 2 -> bin 2 (vert)
    //   tan(pi/10) < v <= tan(3pi/10)  -> k= 1 -> bin 1 (cnt / anti-diag)
    //   |v| <= tan(pi/10)              -> k= 0 -> bin 0 (horiz)
    //   -tan(3pi/10) <= v < -tan(pi/10)-> k=-1 -> bin 4 (no term)
    //   v < -tan(3pi/10)               -> k=-2 -> bin 3 (lead / diag)
    float term = 0.f;
    if (v == v) {  // NaN contributes nothing (matches jnp comparisons)
        float dsum = 0.f;
        bool have = true;
        if (v > 1.3763819204711735f) {
            dsum = s_e[erm][ec0] + ec + s_e[erp][ec0];            // vert
        } else if (v > 0.3249196962329063f) {
            dsum = s_e[erm][ecp] + ec + s_e[erp][ecm];            // anti-diag
        } else if (v >= -0.3249196962329063f) {
            dsum = s_e[er0][ecm] + ec + s_e[er0][ecp];            // horiz
        } else if (v >= -1.3763819204711735f) {
            have = false;                                          // bin 4
        } else {
            dsum = s_e[erm][ecm] + ec + s_e[erp][ecp];            // diag
        }
        if (have) term = ec / (dsum + EPSF);
    }

    // block reduction: wave64 shuffle + cross-wave LDS + one atomic per block
    for (int off = 32; off; off >>= 1) term += __shfl_down(term, off, 64);
    if ((tid & 63) == 0) s_red[tid >> 6] = term;
    __syncthreads();
    if (tid == 0) {
        float b = 0.f;
        #pragma unroll
        for (int i = 0; i < (TX * TY) / 64; ++i) b += s_red[i];
        atomicAdd(out, b);
    }
}

extern "C" void kernel_launch(void* const* d_in, const int* in_sizes, int n_in,
                              void* d_out, int out_size, void* d_ws, size_t ws_size,
                              hipStream_t stream) {
    const float* tru = (const float*)d_in[0];
    const float* prd = (const float*)d_in[1];
    float* out = (float*)d_out;
    hipMemsetAsync(out, 0, sizeof(float), stream);
    dim3 grid(WW / TX, HH / TY, NIMG);
    dim3 block(TX, TY, 1);
    hipLaunchKernelGGL(nms_loss_kernel, grid, block, 0, stream, tru, prd, out);
}

// Round 2
// 101.876 us; speedup vs baseline: 8.3417x; 8.3417x over previous
//
#include <hip/hip_runtime.h>

#define HH 1024
#define WW 1024
#define NIMG 16
// block = 32x8 threads, each thread computes 2x2 pixels -> tile 64x16
#define BTX 32
#define BTY 8
#define TX 64
#define TY 16
#define NBX (WW / TX)
#define NBY (HH / TY)
#define NBLOCKS (NBX * NBY * NIMG)
#define EPSF 1.1920929e-07f

__device__ __forceinline__ int clampi(int v, int hi) {
    return v < 0 ? 0 : (v > hi ? hi : v);
}
__device__ __forceinline__ int refli(int v, int n) {
    // jnp.pad mode='reflect': -1 -> 1, n -> n-2
    return v < 0 ? -v : (v >= n ? 2 * n - 2 - v : v);
}

template <bool USE_WS>
__global__ __launch_bounds__(BTX * BTY) void nms_loss_kernel(
    const float* __restrict__ tru, const float* __restrict__ prd,
    float* __restrict__ partial /* ws or out */)
{
    __shared__ float s_t[TY + 4][TX + 4];   // true, clamp halo 2 (20x68)
    __shared__ float s_gx[TY + 2][TX + 2];  // sobel-x, clamp halo 1 (18x66)
    __shared__ float s_gy[TY + 2][TX + 2];  // sobel-y, clamp halo 1
    __shared__ float s_e[TY + 2][TX + 2];   // exp(pred), reflect halo 1
    __shared__ float s_red[(BTX * BTY) / 64];

    const int tid = threadIdx.y * BTX + threadIdx.x;
    const int bx0 = blockIdx.x * TX;
    const int by0 = blockIdx.y * TY;
    const long imgoff = (long)blockIdx.z * (long)(HH * WW);
    const float* timg = tru + imgoff;
    const float* pimg = prd + imgoff;

    // stage 1a: true tile (replicate halo 2)
    for (int idx = tid; idx < (TY + 4) * (TX + 4); idx += BTX * BTY) {
        int r = idx / (TX + 4), c = idx % (TX + 4);
        int gy = clampi(by0 + r - 2, HH - 1);
        int gx = clampi(bx0 + c - 2, WW - 1);
        s_t[r][c] = timg[gy * WW + gx];
    }
    // stage 1b: exp(pred) tile (reflect halo 1)
    for (int idx = tid; idx < (TY + 2) * (TX + 2); idx += BTX * BTY) {
        int r = idx / (TX + 2), c = idx % (TX + 2);
        int gy = refli(by0 + r - 1, HH);
        int gx = refli(bx0 + c - 1, WW);
        s_e[r][c] = __expf(pimg[gy * WW + gx]);
    }
    __syncthreads();

    // stage 2: first sobel (gx, gy) at tile+halo1 positions.
    // Slot holds value at fully-clamped global coord; nested clamp then map
    // back to s_t slot (slot = g - base + 2) preserves per-stage replicate
    // padding semantics at image borders.
    for (int idx = tid; idx < (TY + 2) * (TX + 2); idx += BTX * BTY) {
        int r = idx / (TX + 2), c = idx % (TX + 2);
        int g1y = clampi(by0 + r - 1, HH - 1);
        int g1x = clampi(bx0 + c - 1, WW - 1);
        int ym = clampi(g1y - 1, HH - 1) - by0 + 2;
        int y0 = g1y - by0 + 2;
        int yp = clampi(g1y + 1, HH - 1) - by0 + 2;
        int xm = clampi(g1x - 1, WW - 1) - bx0 + 2;
        int x0 = g1x - bx0 + 2;
        int xp = clampi(g1x + 1, WW - 1) - bx0 + 2;
        float tmm = s_t[ym][xm], tm0 = s_t[ym][x0], tmp_ = s_t[ym][xp];
        float t0m = s_t[y0][xm],                    t0p = s_t[y0][xp];
        float tpm = s_t[yp][xm], tp0 = s_t[yp][x0], tpp = s_t[yp][xp];
        // normalized sobel (sum |k| = 8)
        s_gx[r][c] = ((tmp_ - tmm) + 2.f * (t0p - t0m) + (tpp - tpm)) * 0.125f;
        s_gy[r][c] = ((tpm - tmm) + 2.f * (tp0 - tm0) + (tpp - tmp_)) * 0.125f;
    }
    __syncthreads();

    // stage 3: per-pixel second gradients, bin, NMS term (2x2 per thread)
    float term = 0.f;
    #pragma unroll
    for (int py = 0; py < 2; ++py) {
        #pragma unroll
        for (int px = 0; px < 2; ++px) {
            const int oy = threadIdx.y * 2 + py;   // 0..TY-1
            const int ox = threadIdx.x * 2 + px;   // 0..TX-1
            const int y = by0 + oy;
            const int x = bx0 + ox;
            int rm = clampi(y - 1, HH - 1) - by0 + 1;
            int r0 = oy + 1;
            int rp = clampi(y + 1, HH - 1) - by0 + 1;
            int cm = clampi(x - 1, WW - 1) - bx0 + 1;
            int c0 = ox + 1;
            int cp = clampi(x + 1, WW - 1) - bx0 + 1;

            float gxx = ((s_gx[rm][cp] - s_gx[rm][cm]) + 2.f * (s_gx[r0][cp] - s_gx[r0][cm])
                       + (s_gx[rp][cp] - s_gx[rp][cm])) * 0.125f;
            float gxy = ((s_gy[rm][cp] - s_gy[rm][cm]) + 2.f * (s_gy[r0][cp] - s_gy[r0][cm])
                       + (s_gy[rp][cp] - s_gy[rp][cm])) * 0.125f;
            float gyy = ((s_gy[rp][cm] - s_gy[rm][cm]) + 2.f * (s_gy[rp][c0] - s_gy[rm][c0])
                       + (s_gy[rp][cp] - s_gy[rm][cp])) * 0.125f;

            float sarg = EPSF - gxy;
            float sgn = (sarg > 0.f) ? 1.f : ((sarg < 0.f) ? -1.f : 0.f);
            float v = gyy * sgn / (gxx + EPSF);

            int erm = refli(y - 1, HH) - by0 + 1;
            int er0 = oy + 1;
            int erp = refli(y + 1, HH) - by0 + 1;
            int ecm = refli(x - 1, WW) - bx0 + 1;
            int ec0 = ox + 1;
            int ecp = refli(x + 1, WW) - bx0 + 1;
            float ec = s_e[er0][ec0];

            // bin = fmod(round(atan(v)*5/pi)+5,5) via tan thresholds
            if (v == v) {  // NaN contributes nothing
                float dsum;
                bool have = true;
                if (v > 1.3763819204711735f) {
                    dsum = s_e[erm][ec0] + ec + s_e[erp][ec0];     // vert (bin 2)
                } else if (v > 0.3249196962329063f) {
                    dsum = s_e[erm][ecp] + ec + s_e[erp][ecm];     // anti-diag (bin 1)
                } else if (v >= -0.3249196962329063f) {
                    dsum = s_e[er0][ecm] + ec + s_e[er0][ecp];     // horiz (bin 0)
                } else if (v >= -1.3763819204711735f) {
                    have = false;                                   // bin 4
                } else {
                    dsum = s_e[erm][ecm] + ec + s_e[erp][ecp];     // diag (bin 3)
                }
                if (have) term += ec / (dsum + EPSF);
            }
        }
    }

    // block reduction: wave64 shuffle + cross-wave LDS
    for (int off = 32; off; off >>= 1) term += __shfl_down(term, off, 64);
    if ((tid & 63) == 0) s_red[tid >> 6] = term;
    __syncthreads();
    if (tid == 0) {
        float b = 0.f;
        #pragma unroll
        for (int i = 0; i < (BTX * BTY) / 64; ++i) b += s_red[i];
        if (USE_WS) {
            const int bid = (blockIdx.z * gridDim.y + blockIdx.y) * gridDim.x + blockIdx.x;
            partial[bid] = b;          // unique slot -> no atomic, no contention
        } else {
            atomicAdd(partial, b);     // fallback (ws too small)
        }
    }
}

__global__ __launch_bounds__(1024) void reduce_kernel(
    const float* __restrict__ partial, float* __restrict__ out)
{
    __shared__ float s_red[16];
    float s = 0.f;
    for (int i = threadIdx.x; i < NBLOCKS; i += 1024) s += partial[i];
    for (int off = 32; off; off >>= 1) s += __shfl_down(s, off, 64);
    if ((threadIdx.x & 63) == 0) s_red[threadIdx.x >> 6] = s;
    __syncthreads();
    if (threadIdx.x == 0) {
        float b = 0.f;
        #pragma unroll
        for (int i = 0; i < 16; ++i) b += s_red[i];
        out[0] = b;
    }
}

extern "C" void kernel_launch(void* const* d_in, const int* in_sizes, int n_in,
                              void* d_out, int out_size, void* d_ws, size_t ws_size,
                              hipStream_t stream) {
    const float* tru = (const float*)d_in[0];
    const float* prd = (const float*)d_in[1];
    float* out = (float*)d_out;
    dim3 grid(NBX, NBY, NIMG);
    dim3 block(BTX, BTY, 1);
    if (ws_size >= (size_t)NBLOCKS * sizeof(float)) {
        float* ws = (float*)d_ws;
        hipLaunchKernelGGL(nms_loss_kernel<true>, grid, block, 0, stream, tru, prd, ws);
        hipLaunchKernelGGL(reduce_kernel, dim3(1), dim3(1024), 0, stream, ws, out);
    } else {
        hipMemsetAsync(out, 0, sizeof(float), stream);
        hipLaunchKernelGGL(nms_loss_kernel<false>, grid, block, 0, stream, tru, prd, out);
    }
}